// Round 7
// baseline (121.467 us; speedup 1.0000x reference)
//
#include <hip/hip_runtime.h>

// QuanvolutionClassifier.
// R3: U = U01 (x) U23 factorization (CX(0,1), CX(2,3) never couple pairs).
// R6: one wave per image row; features FMA'd straight into 10 logit
//     accumulators; no feat LDS, no main barrier.
// R7: U coefficients come from d_ws via WAVE-UNIFORM global loads -> compiler
//     emits s_load -> true SGPRs. (R6 used LDS+readfirstlane; the compiler
//     spilled the 32-float U arrays to scratch: 62 MB/launch of HBM writes.)

#define RPB 4           // rows (images) per block = waves per block
#define NPIX 784
#define NPATCH 196
#define INV4PI 0.07957747154594767f   // 0.5 rad * (1/2pi): pixel -> revolutions

// U[0..15] = U01 row-major, U[16..31] = U23 row-major.
__global__ void build_U_kernel(const float* __restrict__ params, float* __restrict__ U) {
    int t = threadIdx.x;
    if (t >= 8) return;
    int pair = t >> 2;        // 0 -> wires {0,1}, 1 -> wires {2,3}
    int col  = t & 3;         // basis column
    float st[4];
#pragma unroll
    for (int i = 0; i < 4; ++i) st[i] = (i == col) ? 1.0f : 0.0f;
#pragma unroll
    for (int l = 0; l < 4; ++l) {
        float ah = 0.5f * params[l * 4 + pair * 2 + 0];   // high wire of pair
        float al = 0.5f * params[l * 4 + pair * 2 + 1];   // low wire of pair
        float ch = cosf(ah), sh = sinf(ah);
#pragma unroll
        for (int j = 0; j < 2; ++j) {                     // RY on high bit
            float u = st[j], w = st[j + 2];
            st[j]     = ch * u - sh * w;
            st[j + 2] = sh * u + ch * w;
        }
        float cl = cosf(al), sl = sinf(al);
#pragma unroll
        for (int j = 0; j < 4; j += 2) {                  // RY on low bit
            float u = st[j], w = st[j + 1];
            st[j]     = cl * u - sl * w;
            st[j + 1] = sl * u + cl * w;
        }
        float tmp = st[2]; st[2] = st[3]; st[3] = tmp;    // CX: swap |10>,|11>
    }
#pragma unroll
    for (int s = 0; s < 4; ++s) U[pair * 16 + s * 4 + col] = st[s];
}

__launch_bounds__(256, 8)   // 8 waves/EU; U in SGPRs so VGPR ~45 fits the 64 cap
__global__ void quanv_kernel(const float* __restrict__ x,
                             const float* __restrict__ U,
                             const float* __restrict__ W,
                             const float* __restrict__ bias,
                             float* __restrict__ out,
                             int n_rows) {
    const int tid = threadIdx.x;
    const int wid = tid >> 6, lane = tid & 63;
    const int grow = blockIdx.x * RPB + wid;           // one wave per image row
    if (grow >= n_rows) return;

    // wave-uniform addresses (no threadIdx) -> s_load -> SGPRs
    float Ua[16], Ub[16];
#pragma unroll
    for (int i = 0; i < 16; ++i) { Ua[i] = U[i]; Ub[i] = U[16 + i]; }

    const float* xrow = x + (size_t)grow * NPIX;
    const float4* W4 = (const float4*)W;               // W4[o*196 + P]
    float acc[10];
#pragma unroll
    for (int o = 0; o < 10; ++o) acc[o] = 0.f;

#pragma unroll
    for (int it = 0; it < 4; ++it) {
        int P = lane + (it << 6);                      // patch id
        if (P < NPATCH) {
            int Pr = P / 14;                           // magic-mul div
            int Pc = P - Pr * 14;
            const float* px = xrow + Pr * 56 + Pc * 2;
            float2 top = *(const float2*)px;           // pixels [2Pr, 2Pc..2Pc+1]
            float2 bot = *(const float2*)(px + 28);    // pixels [2Pr+1, ...]

            float u;
            u = top.x * INV4PI; float s0 = __builtin_amdgcn_sinf(u), c0 = __builtin_amdgcn_cosf(u);
            u = top.y * INV4PI; float s1 = __builtin_amdgcn_sinf(u), c1 = __builtin_amdgcn_cosf(u);
            u = bot.x * INV4PI; float s2 = __builtin_amdgcn_sinf(u), c2 = __builtin_amdgcn_cosf(u);
            u = bot.y * INV4PI; float s3 = __builtin_amdgcn_sinf(u), c3 = __builtin_amdgcn_cosf(u);

            float pa0 = c0 * c1, pa1 = c0 * s1, pa2 = s0 * c1, pa3 = s0 * s1;
            float pb0 = c2 * c3, pb1 = c2 * s3, pb2 = s2 * c3, pb3 = s2 * s3;
            float qa[4], qb[4];
#pragma unroll
            for (int s = 0; s < 4; ++s) {
                float ya = fmaf(Ua[s * 4 + 3], pa3,
                           fmaf(Ua[s * 4 + 2], pa2,
                           fmaf(Ua[s * 4 + 1], pa1, Ua[s * 4 + 0] * pa0)));
                float yb = fmaf(Ub[s * 4 + 3], pb3,
                           fmaf(Ub[s * 4 + 2], pb2,
                           fmaf(Ub[s * 4 + 1], pb1, Ub[s * 4 + 0] * pb0)));
                qa[s] = ya * ya;
                qb[s] = yb * yb;
            }
            float e0 = (qa[0] + qa[1]) - (qa[2] + qa[3]);
            float e1 = (qa[0] - qa[1]) + (qa[2] - qa[3]);
            float e2 = (qb[0] + qb[1]) - (qb[2] + qb[3]);
            float e3 = (qb[0] - qb[1]) + (qb[2] - qb[3]);

            // fold features straight into the linear layer (W is L1-resident)
#pragma unroll
            for (int o = 0; o < 10; ++o) {
                float4 w = W4[o * NPATCH + P];
                acc[o] = fmaf(e0, w.x, fmaf(e1, w.y, fmaf(e2, w.z, fmaf(e3, w.w, acc[o]))));
            }
        }
    }

    // wave-level reduction of the 10 partial logits
#pragma unroll
    for (int o = 0; o < 10; ++o) {
        acc[o] += __shfl_xor(acc[o], 32, 64);
        acc[o] += __shfl_xor(acc[o], 16, 64);
        acc[o] += __shfl_xor(acc[o], 8, 64);
        acc[o] += __shfl_xor(acc[o], 4, 64);
        acc[o] += __shfl_xor(acc[o], 2, 64);
        acc[o] += __shfl_xor(acc[o], 1, 64);
    }
    if (lane == 0) {
        float lg[10], mx = -1e30f;
#pragma unroll
        for (int o = 0; o < 10; ++o) { lg[o] = acc[o] + bias[o]; mx = fmaxf(mx, lg[o]); }
        float sum = 0.f;
#pragma unroll
        for (int o = 0; o < 10; ++o) sum += __expf(lg[o] - mx);
        float lse = mx + __logf(sum);
#pragma unroll
        for (int o = 0; o < 10; ++o) out[(size_t)grow * 10 + o] = lg[o] - lse;
    }
}

extern "C" void kernel_launch(void* const* d_in, const int* in_sizes, int n_in,
                              void* d_out, int out_size, void* d_ws, size_t ws_size,
                              hipStream_t stream) {
    const float* x      = (const float*)d_in[0];
    const float* params = (const float*)d_in[1];
    const float* W      = (const float*)d_in[2];
    const float* b      = (const float*)d_in[3];
    float* out = (float*)d_out;
    float* U   = (float*)d_ws;   // 32 floats: U01 then U23

    int n_rows = in_sizes[0] / NPIX;   // 8192
    hipLaunchKernelGGL(build_U_kernel, dim3(1), dim3(64), 0, stream, params, U);
    int nblocks = (n_rows + RPB - 1) / RPB;
    hipLaunchKernelGGL(quanv_kernel, dim3(nblocks), dim3(256), 0, stream,
                       x, U, W, b, out, n_rows);
}

// Round 9
// 89.957 us; speedup vs baseline: 1.3503x; 1.3503x over previous
//
#include <hip/hip_runtime.h>

// QuanvolutionClassifier — single fused kernel (replay-safe), barrier-light.
// R3: U = U01 (x) U23 factorization (CX(0,1), CX(2,3) never couple pairs).
// R6: one wave per image row; features FMA'd straight into 10 logit accums;
//     no feat LDS, no phase-2 pass.
// R8 lesson: two-kernel d_ws handoff diverges under graph replay (cross-XCD /
//     scalar-cache visibility of the freshly-written U). Build U IN-kernel.
// R9: __launch_bounds__(256,4) — the R6 spill (78 MB scratch!) was the 64-VGPR
//     cap from (256,8); 128-VGPR cap fits the ~70-reg live set with NO spill.

#define RPB 4           // rows (images) per block = waves per block
#define NPIX 784
#define NPATCH 196
#define INV4PI 0.07957747154594767f   // 0.5 rad * (1/2pi): pixel -> revolutions

__device__ __forceinline__ float rfl(float v) {
    return __uint_as_float(__builtin_amdgcn_readfirstlane(__float_as_uint(v)));
}

__launch_bounds__(256, 4)   // 128-VGPR cap: no scratch spill; 16 waves/CU
__global__ void quanv_kernel(const float* __restrict__ x,
                             const float* __restrict__ params,
                             const float* __restrict__ W,
                             const float* __restrict__ bias,
                             float* __restrict__ out,
                             int n_rows) {
    __shared__ float Ush[32];                          // U01 | U23
    const int tid = threadIdx.x;

    // ---- build U01/U23 (8 lanes, ~100 FLOPs, redundant per block) ----
    if (tid < 8) {
        int pair = tid >> 2;      // 0 -> wires {0,1}, 1 -> wires {2,3}
        int col  = tid & 3;       // basis column
        float st[4];
#pragma unroll
        for (int i = 0; i < 4; ++i) st[i] = (i == col) ? 1.0f : 0.0f;
#pragma unroll
        for (int l = 0; l < 4; ++l) {
            float ah = 0.5f * params[l * 4 + pair * 2 + 0];
            float al = 0.5f * params[l * 4 + pair * 2 + 1];
            float ch = cosf(ah), sh = sinf(ah);
#pragma unroll
            for (int j = 0; j < 2; ++j) {                     // RY on high bit
                float u = st[j], w = st[j + 2];
                st[j]     = ch * u - sh * w;
                st[j + 2] = sh * u + ch * w;
            }
            float cl = cosf(al), sl = sinf(al);
#pragma unroll
            for (int j = 0; j < 4; j += 2) {                  // RY on low bit
                float u = st[j], w = st[j + 1];
                st[j]     = cl * u - sl * w;
                st[j + 1] = sl * u + cl * w;
            }
            float tmp = st[2]; st[2] = st[3]; st[3] = tmp;    // CX: swap |10>,|11>
        }
#pragma unroll
        for (int s = 0; s < 4; ++s) Ush[pair * 16 + s * 4 + col] = st[s];
    }
    __syncthreads();   // publish U; only barrier in the kernel

    // pin the 32 wave-uniform coeffs into SGPRs
    float Ua[16], Ub[16];
#pragma unroll
    for (int i = 0; i < 16; ++i) { Ua[i] = rfl(Ush[i]); Ub[i] = rfl(Ush[16 + i]); }

    const int wid = tid >> 6, lane = tid & 63;
    const int grow = blockIdx.x * RPB + wid;           // one wave per image row
    if (grow >= n_rows) return;

    const float* xrow = x + (size_t)grow * NPIX;
    const float4* W4 = (const float4*)W;               // W4[o*196 + P]
    float acc[10];
#pragma unroll
    for (int o = 0; o < 10; ++o) acc[o] = 0.f;

#pragma unroll
    for (int it = 0; it < 4; ++it) {
        int P = lane + (it << 6);                      // patch id
        if (P < NPATCH) {
            int Pr = P / 14;                           // magic-mul div
            int Pc = P - Pr * 14;
            const float* px = xrow + Pr * 56 + Pc * 2;
            float2 top = *(const float2*)px;           // pixels [2Pr, 2Pc..2Pc+1]
            float2 bot = *(const float2*)(px + 28);    // pixels [2Pr+1, ...]

            float u;
            u = top.x * INV4PI; float s0 = __builtin_amdgcn_sinf(u), c0 = __builtin_amdgcn_cosf(u);
            u = top.y * INV4PI; float s1 = __builtin_amdgcn_sinf(u), c1 = __builtin_amdgcn_cosf(u);
            u = bot.x * INV4PI; float s2 = __builtin_amdgcn_sinf(u), c2 = __builtin_amdgcn_cosf(u);
            u = bot.y * INV4PI; float s3 = __builtin_amdgcn_sinf(u), c3 = __builtin_amdgcn_cosf(u);

            float pa0 = c0 * c1, pa1 = c0 * s1, pa2 = s0 * c1, pa3 = s0 * s1;
            float pb0 = c2 * c3, pb1 = c2 * s3, pb2 = s2 * c3, pb3 = s2 * s3;
            float qa[4], qb[4];
#pragma unroll
            for (int s = 0; s < 4; ++s) {
                float ya = fmaf(Ua[s * 4 + 3], pa3,
                           fmaf(Ua[s * 4 + 2], pa2,
                           fmaf(Ua[s * 4 + 1], pa1, Ua[s * 4 + 0] * pa0)));
                float yb = fmaf(Ub[s * 4 + 3], pb3,
                           fmaf(Ub[s * 4 + 2], pb2,
                           fmaf(Ub[s * 4 + 1], pb1, Ub[s * 4 + 0] * pb0)));
                qa[s] = ya * ya;
                qb[s] = yb * yb;
            }
            float e0 = (qa[0] + qa[1]) - (qa[2] + qa[3]);
            float e1 = (qa[0] - qa[1]) + (qa[2] - qa[3]);
            float e2 = (qb[0] + qb[1]) - (qb[2] + qb[3]);
            float e3 = (qb[0] - qb[1]) + (qb[2] - qb[3]);

            // fold features straight into the linear layer (W is L1-resident)
#pragma unroll
            for (int o = 0; o < 10; ++o) {
                float4 w = W4[o * NPATCH + P];
                acc[o] = fmaf(e0, w.x, fmaf(e1, w.y, fmaf(e2, w.z, fmaf(e3, w.w, acc[o]))));
            }
        }
    }

    // wave-level reduction of the 10 partial logits
#pragma unroll
    for (int o = 0; o < 10; ++o) {
        acc[o] += __shfl_xor(acc[o], 32, 64);
        acc[o] += __shfl_xor(acc[o], 16, 64);
        acc[o] += __shfl_xor(acc[o], 8, 64);
        acc[o] += __shfl_xor(acc[o], 4, 64);
        acc[o] += __shfl_xor(acc[o], 2, 64);
        acc[o] += __shfl_xor(acc[o], 1, 64);
    }
    if (lane == 0) {
        float lg[10], mx = -1e30f;
#pragma unroll
        for (int o = 0; o < 10; ++o) { lg[o] = acc[o] + bias[o]; mx = fmaxf(mx, lg[o]); }
        float sum = 0.f;
#pragma unroll
        for (int o = 0; o < 10; ++o) sum += __expf(lg[o] - mx);
        float lse = mx + __logf(sum);
#pragma unroll
        for (int o = 0; o < 10; ++o) out[(size_t)grow * 10 + o] = lg[o] - lse;
    }
}

extern "C" void kernel_launch(void* const* d_in, const int* in_sizes, int n_in,
                              void* d_out, int out_size, void* d_ws, size_t ws_size,
                              hipStream_t stream) {
    const float* x      = (const float*)d_in[0];
    const float* params = (const float*)d_in[1];
    const float* W      = (const float*)d_in[2];
    const float* b      = (const float*)d_in[3];
    float* out = (float*)d_out;

    int n_rows = in_sizes[0] / NPIX;   // 8192
    int nblocks = (n_rows + RPB - 1) / RPB;
    hipLaunchKernelGGL(quanv_kernel, dim3(nblocks), dim3(256), 0, stream,
                       x, params, W, b, out, n_rows);
}